// Round 6
// baseline (25763.895 us; speedup 1.0000x reference)
//
#include <hip/hip_runtime.h>
#include <hip/hip_fp16.h>
#include <hip/hip_cooperative_groups.h>

namespace cg = cooperative_groups;

#define NB 128
#define ND 1280
#define NK 49
#define NV 10000
#define NT 40
#define N4D 5120
#define GRID 512

typedef unsigned long long u64;

struct P {
  const float *ch, *pooled, *Wih, *Whh, *bih, *bhh, *Wq, *bq, *Wk, *bk, *Wv, *bv,
              *Wh, *bh, *Wc, *bc, *Wp, *bp, *embed;
  float *outp;
  float *kmatT, *vmat, *h_st, *c_st, *x_st, *h_new, *c_new,
        *gpart, *lpart, *qpart, *attb, *g2part;
  u64 *amax;
  __half *stage;
  int staged;
};

// ---------------- fp32 GEMM core: M=128 fixed, N-tile=64 ----
__device__ __forceinline__ void gemm_core(
    const float* __restrict__ A0, const float* __restrict__ A1, int asplit, int lda,
    const float* __restrict__ B0, const float* __restrict__ B1, int bsplit, int ldb,
    int n0, int N, int kbase, int kc, float* __restrict__ C)
{
  __shared__ float Al[2][16][132];
  __shared__ float Bl[2][16][68];
  const int tid = threadIdx.x;
  const int tn = tid & 15, tm = tid >> 4;
  float acc[8][4];
#pragma unroll
  for (int i = 0; i < 8; ++i)
#pragma unroll
    for (int j = 0; j < 4; ++j) acc[i][j] = 0.f;

  const int am  = tid >> 1;
  const int ac0 = (tid & 1) * 8;
  const int br  = tid >> 4;
  const int bc  = (tid & 15) * 4;
  const int bcol = n0 + bc;
  const int ntile = kc >> 4;

  float4 ra0, ra1, rb;

  auto load_tile = [&](int t) {
    const int kg = kbase + (t << 4);
    const float* Ab = (kg < asplit) ? (A0 + kg) : (A1 + (kg - asplit));
    const float* Bb = (kg < bsplit) ? (B0 + (size_t)kg * ldb)
                                    : (B1 + (size_t)(kg - bsplit) * ldb);
    ra0 = *(const float4*)(Ab + (size_t)am * lda + ac0);
    ra1 = *(const float4*)(Ab + (size_t)am * lda + ac0 + 4);
    if (bcol < N) rb = *(const float4*)(Bb + (size_t)br * ldb + bcol);
    else rb = make_float4(0.f, 0.f, 0.f, 0.f);
  };
  auto store_tile = [&](int buf) {
    Al[buf][ac0 + 0][am] = ra0.x; Al[buf][ac0 + 1][am] = ra0.y;
    Al[buf][ac0 + 2][am] = ra0.z; Al[buf][ac0 + 3][am] = ra0.w;
    Al[buf][ac0 + 4][am] = ra1.x; Al[buf][ac0 + 5][am] = ra1.y;
    Al[buf][ac0 + 6][am] = ra1.z; Al[buf][ac0 + 7][am] = ra1.w;
    *(float4*)&Bl[buf][br][bc] = rb;
  };

  load_tile(0); store_tile(0); __syncthreads();
  for (int t = 0; t < ntile; ++t) {
    if (t + 1 < ntile) load_tile(t + 1);
    const int buf = t & 1;
#pragma unroll
    for (int kk = 0; kk < 16; ++kk) {
      const float4 a0 = *(const float4*)&Al[buf][kk][tm * 8];
      const float4 a1 = *(const float4*)&Al[buf][kk][tm * 8 + 4];
      const float4 b4 = *(const float4*)&Bl[buf][kk][tn * 4];
      const float amv[8] = {a0.x, a0.y, a0.z, a0.w, a1.x, a1.y, a1.z, a1.w};
      const float bvv[4] = {b4.x, b4.y, b4.z, b4.w};
#pragma unroll
      for (int i = 0; i < 8; ++i)
#pragma unroll
        for (int j = 0; j < 4; ++j)
          acc[i][j] = fmaf(amv[i], bvv[j], acc[i][j]);
    }
    __syncthreads();
    if (t + 1 < ntile) { store_tile((t + 1) & 1); __syncthreads(); }
  }
  const int ccol = n0 + tn * 4;
  if (ccol < N) {
#pragma unroll
    for (int i = 0; i < 8; ++i) {
      float4 v = make_float4(acc[i][0], acc[i][1], acc[i][2], acc[i][3]);
      *(float4*)(C + (size_t)(tm * 8 + i) * N + ccol) = v;
    }
  }
}

__device__ __forceinline__ u64 pack_max(float v, int n) {
  unsigned u = __float_as_uint(v);
  u = (u & 0x80000000u) ? ~u : (u | 0x80000000u);
  return ((u64)u << 32) | (u64)(0xFFFFFFFFu - (unsigned)n);
}

// ---- phase 2: LSTM pointwise (6 gate partials) + zero amax ----
__device__ void ph_lstm(int blk, const P& p) {
  int tid = threadIdx.x;
  for (int idx = blk * 256 + tid; idx < NB * ND; idx += GRID * 256) {
    if (idx < NB) p.amax[idx] = 0ULL;
    int b = idx / ND, d = idx % ND;
    const float* gp = p.gpart + (size_t)b * N4D;
    float gi = p.bih[d]          + p.bhh[d];
    float gf = p.bih[ND + d]     + p.bhh[ND + d];
    float gg = p.bih[2 * ND + d] + p.bhh[2 * ND + d];
    float go = p.bih[3 * ND + d] + p.bhh[3 * ND + d];
#pragma unroll
    for (int s = 0; s < 6; ++s) {
      const float* q = gp + (size_t)s * NB * N4D;
      gi += q[d]; gf += q[ND + d]; gg += q[2 * ND + d]; go += q[3 * ND + d];
    }
    float c = p.c_st[idx];
    float si = 1.f / (1.f + expf(-gi));
    float sf = 1.f / (1.f + expf(-gf));
    float so = 1.f / (1.f + expf(-go));
    float cnew = sf * c + si * tanhf(gg);
    p.c_new[idx] = cnew; p.h_new[idx] = so * tanhf(cnew);
  }
}

// ---- phase 4a: logits reduce (3 partials) + fp16 stage + argmax ----
__device__ void ph_lred(int b, int nbeg, int step, const P& p) {
  __shared__ u64 red[256];
  int tid = threadIdx.x;
  u64 best = 0ULL;
  for (int n = nbeg + tid; n < nbeg + 5000; n += 256) {
    float v = p.bp[n];
#pragma unroll
    for (int s = 0; s < 3; ++s) v += p.lpart[(size_t)s * NB * NV + (size_t)b * NV + n];
    if (p.staged) p.stage[(size_t)(step + 1) * NB * NV + (size_t)b * NV + n] = __float2half(v);
    else p.outp[((size_t)b * NV + n) * NT + step + 1] = v;
    u64 q = pack_max(v, n);
    best = best > q ? best : q;
  }
  red[tid] = best; __syncthreads();
  for (int off = 128; off > 0; off >>= 1) {
    if (tid < off) { u64 o = red[tid + off]; if (o > red[tid]) red[tid] = o; }
    __syncthreads();
  }
  if (tid == 0) atomicMax(p.amax + b, red[0]);
}

// ---- phase 5a: attention for one batch row (6 q-partials) ----
__device__ void ph_attn(int bb, const P& p) {
  __shared__ float qh[ND], qc[ND];
  __shared__ float sc[2][64];
  __shared__ float wl[2][64];
  int tid = threadIdx.x;
  for (int d = tid; d < ND; d += 256) {
    float ah = p.bq[d], ac = p.bq[d];
#pragma unroll
    for (int s = 0; s < 6; ++s) {
      ah += p.qpart[(size_t)s * 256 * ND + (size_t)bb * ND + d];
      ac += p.qpart[(size_t)s * 256 * ND + (size_t)(NB + bb) * ND + d];
    }
    qh[d] = tanhf(ah); qc[d] = tanhf(ac);
  }
  __syncthreads();
  int w = tid >> 6, lane = tid & 63;
  for (int kk = w; kk < NK; kk += 4) {
    const float4* kr = (const float4*)(p.kmatT + ((size_t)bb * NK + kk) * ND);
    float ah = 0.f, ac = 0.f;
#pragma unroll
    for (int c = 0; c < 5; ++c) {
      float4 kv = kr[c * 64 + lane];
      const float4 q4h = *(const float4*)&qh[(c * 64 + lane) * 4];
      const float4 q4c = *(const float4*)&qc[(c * 64 + lane) * 4];
      ah += kv.x * q4h.x + kv.y * q4h.y + kv.z * q4h.z + kv.w * q4h.w;
      ac += kv.x * q4c.x + kv.y * q4c.y + kv.z * q4c.z + kv.w * q4c.w;
    }
#pragma unroll
    for (int off = 32; off > 0; off >>= 1) {
      ah += __shfl_down(ah, off);
      ac += __shfl_down(ac, off);
    }
    if (lane == 0) { sc[0][kk] = ah / 7.0f; sc[1][kk] = ac / 7.0f; }
  }
  __syncthreads();
  if (w < 2) {
    float s = (lane < NK) ? sc[w][lane] : -3.4e38f;
    float mx = s;
#pragma unroll
    for (int off = 32; off > 0; off >>= 1) mx = fmaxf(mx, __shfl_xor(mx, off));
    float e = (lane < NK) ? expf(s - mx) : 0.f;
    float sum = e;
#pragma unroll
    for (int off = 32; off > 0; off >>= 1) sum += __shfl_xor(sum, off);
    wl[w][lane] = (lane < NK) ? e / sum : 0.f;
  }
  __syncthreads();
  for (int d = tid; d < ND; d += 256) {
    const float4* vr = (const float4*)(p.vmat + ((size_t)bb * ND + d) * 52);
    float ah = 0.f, ac = 0.f;
#pragma unroll
    for (int c4 = 0; c4 < 13; ++c4) {
      float4 v = vr[c4];
      ah += wl[0][c4 * 4 + 0] * v.x + wl[0][c4 * 4 + 1] * v.y
          + wl[0][c4 * 4 + 2] * v.z + wl[0][c4 * 4 + 3] * v.w;
      ac += wl[1][c4 * 4 + 0] * v.x + wl[1][c4 * 4 + 1] * v.y
          + wl[1][c4 * 4 + 2] * v.z + wl[1][c4 * 4 + 3] * v.w;
    }
    p.attb[(size_t)bb * ND + d] = ah;
    p.attb[(size_t)(NB + bb) * ND + d] = ac;
  }
}

// ---- phase dispatcher ----
__device__ void do_phase(int phase, int blk, int step, const P& p) {
  const int tid = threadIdx.x;
  switch (phase) {
    case 1:  // gates: 80 N-tiles x splitK6 (432x5 + 400)
      if (blk < 480) {
        int tile = blk / 6, sk = blk % 6;
        int kbase = sk * 432, kc = (sk == 5) ? 400 : 432;
        gemm_core(p.x_st, p.h_st, ND, ND, p.Wih, p.Whh, ND, N4D,
                  tile * 64, N4D, kbase, kc, p.gpart + (size_t)sk * NB * N4D);
      }
      break;
    case 2: ph_lstm(blk, p); break;
    case 3:  // logits: 157 N-tiles x splitK3 (432,432,416)
      if (blk < 471) {
        int tile = blk / 3, sk = blk % 3;
        int kbase = sk * 432, kc = (sk == 2) ? 416 : 432;
        gemm_core(p.h_new, p.h_new, 1 << 28, ND, p.Wp, p.Wp, 1 << 28, NV,
                  tile * 64, NV, kbase, kc, p.lpart + (size_t)sk * NB * NV);
      }
      break;
    case 4:  // lred (256 blocks) || qgemm (240 blocks)
      if (blk < 256) ph_lred(blk >> 1, (blk & 1) * 5000, step, p);
      else if (blk >= 272) {
        int q = blk - 272, z = q / 120, r = q % 120;
        int tile = r / 6, sk = r % 6;
        int kbase = sk * 224, kc = (sk == 5) ? 160 : 224;
        const float* A = z ? p.c_new : p.h_new;
        gemm_core(A, A, 1 << 28, ND, p.Wq, p.Wq, 1 << 28, ND,
                  tile * 64, ND, kbase, kc,
                  p.qpart + (size_t)sk * 256 * ND + (size_t)z * NB * ND);
      }
      break;
    case 5:  // attn (128) || x gather (32)
      if (blk < NB) ph_attn(blk, p);
      else if (blk < 160) {
        int base = (blk - NB) * 5120;
        for (int i = base + tid; i < base + 5120; i += 256) {
          int b = i / ND, d = i % ND;
          int n = (int)(0xFFFFFFFFu - (unsigned)(p.amax[b] & 0xFFFFFFFFULL));
          p.x_st[i] = p.embed[(size_t)n * ND + d];
        }
      }
      break;
    case 6:  // gating gemms: 2z x 20 tiles x splitK12 (224x8 + 192x4)
      if (blk < 480) {
        int z = blk / 240, r = blk % 240;
        int tile = r / 12, sk = r % 12;
        int kbase = (sk < 8) ? sk * 224 : 1792 + (sk - 8) * 192;
        int kc = (sk < 8) ? 224 : 192;
        const float* A0 = p.attb + (size_t)z * NB * ND;
        const float* A1 = z ? p.c_new : p.h_new;
        const float* Bw = z ? p.Wc : p.Wh;
        gemm_core(A0, A1, ND, ND, Bw, Bw, 1 << 28, ND, tile * 64, ND, kbase, kc,
                  p.g2part + (size_t)z * 12 * NB * ND + (size_t)sk * NB * ND);
      }
      break;
    case 7:  // gating reduce (12 partials) -> tanh -> h_st/c_st
      for (int idx = blk * 256 + tid; idx < 2 * NB * ND; idx += GRID * 256) {
        int z = idx / (NB * ND); int rem = idx - z * NB * ND; int d = rem % ND;
        float v = z ? p.bc[d] : p.bh[d];
        const float* q = p.g2part + (size_t)z * 12 * NB * ND + rem;
#pragma unroll
        for (int s = 0; s < 12; ++s) v += q[(size_t)s * NB * ND];
        v = tanhf(v);
        if (z) p.c_st[rem] = v; else p.h_st[rem] = v;
      }
      break;
  }
}

// ---- the persistent cooperative loop ----
__global__ __launch_bounds__(256, 2) void k_loop(P p) {
  cg::grid_group g = cg::this_grid();
  const int blk = blockIdx.x;
  for (int s = 0; s < NT - 1; ++s) {
    do_phase(1, blk, s, p); g.sync();
    do_phase(2, blk, s, p); g.sync();
    do_phase(3, blk, s, p); g.sync();
    do_phase(4, blk, s, p); g.sync();
    do_phase(5, blk, s, p); g.sync();
    do_phase(6, blk, s, p); g.sync();
    do_phase(7, blk, s, p); g.sync();
  }
}

// ---- fallback path: same phases as plain launches ----
__global__ __launch_bounds__(256, 2) void f_phase(int phase, int step, P p) {
  do_phase(phase, blockIdx.x, step, p);
}

// ---- init: h=c=pooled, x=embed[SOS=0] ----
__global__ __launch_bounds__(256) void k_init(const float* __restrict__ pooled,
    const float* __restrict__ embed, float* __restrict__ h, float* __restrict__ c,
    float* __restrict__ x)
{
  int idx = blockIdx.x * 256 + threadIdx.x;   // < 163840 exactly
  float p = pooled[idx];
  h[idx] = p; c[idx] = p;
  x[idx] = embed[idx % ND];
}

// ---- precompute kmatT[b][k][d] = tanh(ch@Wk+bk)^T, vmat[b][d][0..51] ----
__global__ __launch_bounds__(256) void k_kv(const float* __restrict__ ch,
    const float* __restrict__ Wk, const float* __restrict__ bk,
    const float* __restrict__ Wv, const float* __restrict__ bv,
    float* __restrict__ kmatT, float* __restrict__ vmat)
{
  __shared__ float sbuf[256 * NK];
  __shared__ float Wkl[NK * NK], Wvl[NK * NK], bkl[64], bvl[64];
  int b = blockIdx.y, d0 = blockIdx.x * 256, tid = threadIdx.x;
  for (int i = tid; i < NK * NK; i += 256) { Wkl[i] = Wk[i]; Wvl[i] = Wv[i]; }
  if (tid < NK) { bkl[tid] = bk[tid]; bvl[tid] = bv[tid]; }
  const size_t chbase = ((size_t)b * ND + d0) * NK;
  for (int i = tid; i < 256 * NK; i += 256) sbuf[i] = ch[chbase + i];
  __syncthreads();
  float rr[NK];
#pragma unroll
  for (int k = 0; k < NK; ++k) rr[k] = sbuf[tid * NK + k];
  size_t vb = ((size_t)b * ND + d0 + tid) * 52;
  for (int j = 0; j < NK; ++j) {
    float a = bvl[j];
#pragma unroll
    for (int k = 0; k < NK; ++k) a = fmaf(rr[k], Wvl[k * NK + j], a);
    vmat[vb + j] = tanhf(a);
  }
  vmat[vb + 49] = 0.f; vmat[vb + 50] = 0.f; vmat[vb + 51] = 0.f;
  __syncthreads();
  for (int j = 0; j < NK; ++j) {
    float a = bkl[j];
#pragma unroll
    for (int k = 0; k < NK; ++k) a = fmaf(rr[k], Wkl[k * NK + j], a);
    sbuf[j * 256 + tid] = tanhf(a);
  }
  __syncthreads();
  for (int i = tid; i < NK * 256; i += 256) {
    int j = i >> 8, dd = i & 255;
    kmatT[((size_t)b * NK + j) * ND + d0 + dd] = sbuf[i];
  }
}

// ---- t=0 logits: embed[SOS]@Wp + bp ----
__global__ __launch_bounds__(256) void k_l0(const float* __restrict__ embed,
    const float* __restrict__ Wp, const float* __restrict__ bp,
    __half* __restrict__ stage, float* __restrict__ outp, int staged)
{
  __shared__ float e0[ND];
  int tid = threadIdx.x;
  for (int i = tid; i < ND; i += 256) e0[i] = embed[i];
  __syncthreads();
  int n = blockIdx.x * 256 + tid;
  if (n >= NV) return;
  float a = bp[n];
  for (int d = 0; d < ND; ++d) a = fmaf(e0[d], Wp[(size_t)d * NV + n], a);
  if (staged) {
    for (int b = 0; b < NB; ++b) stage[(size_t)b * NV + n] = __float2half(a);
  } else {
    for (int b = 0; b < NB; ++b) outp[((size_t)b * NV + n) * NT] = a;
  }
}

// ---- final transpose: stage[t][b][n] (fp16) -> out[b][n][t] (fp32) ----
__global__ __launch_bounds__(256) void k_tr(const __half* __restrict__ stage,
    float* __restrict__ outp)
{
  __shared__ float tl[64][41];
  int b = blockIdx.y, n0 = blockIdx.x * 64, tid = threadIdx.x;
  for (int i = tid; i < 2560; i += 256) {
    int t = i >> 6, n = i & 63;
    float v = (n0 + n < NV)
        ? __half2float(stage[(size_t)t * NB * NV + (size_t)b * NV + n0 + n]) : 0.f;
    tl[n][t] = v;
  }
  __syncthreads();
  for (int i = tid; i < 640; i += 256) {
    int row = i / 10, c4 = i % 10;
    if (n0 + row < NV) {
      float4 v = make_float4(tl[row][c4 * 4], tl[row][c4 * 4 + 1],
                             tl[row][c4 * 4 + 2], tl[row][c4 * 4 + 3]);
      *(float4*)(outp + ((size_t)b * NV + n0 + row) * NT + c4 * 4) = v;
    }
  }
}

extern "C" void kernel_launch(void* const* d_in, const int* in_sizes, int n_in,
                              void* d_out, int out_size, void* d_ws, size_t ws_size,
                              hipStream_t stream) {
  P p;
  p.ch     = (const float*)d_in[0];
  p.pooled = (const float*)d_in[1];
  p.Wih    = (const float*)d_in[2];
  p.Whh    = (const float*)d_in[3];
  p.bih    = (const float*)d_in[4];
  p.bhh    = (const float*)d_in[5];
  p.Wq     = (const float*)d_in[6];
  p.bq     = (const float*)d_in[7];
  p.Wk     = (const float*)d_in[8];
  p.bk     = (const float*)d_in[9];
  p.Wv     = (const float*)d_in[10];
  p.bv     = (const float*)d_in[11];
  p.Wh     = (const float*)d_in[12];
  p.bh     = (const float*)d_in[13];
  p.Wc     = (const float*)d_in[14];
  p.bc     = (const float*)d_in[15];
  p.Wp     = (const float*)d_in[16];
  p.bp     = (const float*)d_in[17];
  p.embed  = (const float*)d_in[18];
  p.outp   = (float*)d_out;

  char* w = (char*)d_ws;
  size_t off = 0;
  auto alloc = [&](size_t bytes) {
    void* q = w + off; off += (bytes + 255) & ~(size_t)255; return q;
  };
  p.kmatT  = (float*)alloc((size_t)NB * NK * ND * 4);
  p.vmat   = (float*)alloc((size_t)NB * ND * 52 * 4);
  p.h_st   = (float*)alloc((size_t)NB * ND * 4);
  p.c_st   = (float*)alloc((size_t)NB * ND * 4);
  p.x_st   = (float*)alloc((size_t)NB * ND * 4);
  p.h_new  = (float*)alloc((size_t)NB * ND * 4);
  p.c_new  = (float*)alloc((size_t)NB * ND * 4);
  p.gpart  = (float*)alloc((size_t)6 * NB * N4D * 4);
  p.lpart  = (float*)alloc((size_t)3 * NB * NV * 4);
  p.qpart  = (float*)alloc((size_t)6 * 256 * ND * 4);
  p.attb   = (float*)alloc((size_t)256 * ND * 4);
  p.g2part = (float*)alloc((size_t)2 * 12 * NB * ND * 4);
  p.amax   = (u64*)alloc((size_t)NB * 8);
  p.stage  = (__half*)alloc((size_t)NT * NB * NV * 2);
  p.staged = (ws_size >= off) ? 1 : 0;

  k_init<<<640, 256, 0, stream>>>(p.pooled, p.embed, p.h_st, p.c_st, p.x_st);
  k_kv<<<dim3(5, NB), 256, 0, stream>>>(p.ch, p.Wk, p.bk, p.Wv, p.bv, p.kmatT, p.vmat);
  k_l0<<<40, 256, 0, stream>>>(p.embed, p.Wp, p.bp, p.stage, p.outp, p.staged);

  void* args[] = { &p };
  hipError_t e = hipLaunchCooperativeKernel((const void*)k_loop, dim3(GRID),
                                            dim3(256), args, 0, stream);
  if (e != hipSuccess) {
    (void)hipGetLastError();  // clear error state; fall back to plain launches
    for (int s = 0; s < NT - 1; ++s)
      for (int phase = 1; phase <= 7; ++phase)
        f_phase<<<GRID, 256, 0, stream>>>(phase, s, p);
  }

  if (p.staged) k_tr<<<dim3(157, NB), 256, 0, stream>>>(p.stage, p.outp);
}